// Round 1
// baseline (41.771 us; speedup 1.0000x reference)
//
#include <hip/hip_runtime.h>

#define TILE 256
#define G_CONST 0.001f
#define EPS_CONST 1e-6f

__global__ __launch_bounds__(256, 4)
void grav_kernel(const float* __restrict__ q, const float* __restrict__ m,
                 float* __restrict__ out, int B, int N, int tiles_per_split) {
  const int b   = blockIdx.z;
  const int tid = threadIdx.x;
  const int i   = blockIdx.x * TILE + tid;

  __shared__ float4 tile[TILE];
  __shared__ float  wsum[4];

  const float* qb = q + (size_t)b * N * 3;

  float xi = 0.f, yi = 0.f, zi = 0.f, mi = 0.f;
  if (i < N) {
    xi = qb[3 * i + 0];
    yi = qb[3 * i + 1];
    zi = qb[3 * i + 2];
    mi = m[i];
  }

  const int njt = (N + TILE - 1) / TILE;
  const int t0  = blockIdx.y * tiles_per_split;
  const int t1  = min(t0 + tiles_per_split, njt);

  float acc = 0.f;
  for (int t = t0; t < t1; ++t) {
    const int j = t * TILE + tid;
    float4 p;
    if (j < N) {
      p = make_float4(qb[3 * j + 0], qb[3 * j + 1], qb[3 * j + 2], m[j]);
    } else {
      p = make_float4(0.f, 0.f, 0.f, 0.f);  // m=0 -> contributes nothing
    }
    __syncthreads();   // previous tile fully consumed
    tile[tid] = p;
    __syncthreads();   // tile visible to all

#pragma unroll 8
    for (int k = 0; k < TILE; ++k) {
      const float4 pj = tile[k];            // broadcast read, no conflicts
      const float dx = xi - pj.x;
      const float dy = yi - pj.y;
      const float dz = zi - pj.z;
      const float r2 = fmaf(dx, dx, fmaf(dy, dy, fmaf(dz, dz, EPS_CONST)));
      acc = fmaf(pj.w, __builtin_amdgcn_rsqf(r2), acc);
    }
  }

  // Remove the self-interaction term if j==i fell inside this block's j-range.
  // In-loop it evaluated to mi * rsq(EPS); subtract the identical quantity.
  if (i < N && i >= t0 * TILE && i < t1 * TILE) {
    acc -= mi * __builtin_amdgcn_rsqf(EPS_CONST);
  }
  acc *= mi;

  // Block reduction: 64-lane shuffle reduce, then across the 4 waves via LDS.
#pragma unroll
  for (int off = 32; off > 0; off >>= 1) acc += __shfl_down(acc, off);
  const int wid  = tid >> 6;
  const int lane = tid & 63;
  if (lane == 0) wsum[wid] = acc;
  __syncthreads();
  if (tid == 0) {
    const float s = (wsum[0] + wsum[1]) + (wsum[2] + wsum[3]);
    atomicAdd(out + b, s * (-0.5f * G_CONST));
  }
}

extern "C" void kernel_launch(void* const* d_in, const int* in_sizes, int n_in,
                              void* d_out, int out_size, void* d_ws, size_t ws_size,
                              hipStream_t stream) {
  const float* q = (const float*)d_in[0];
  const float* m = (const float*)d_in[1];
  float* out = (float*)d_out;

  const int N = in_sizes[1];
  const int B = in_sizes[0] / (N * 3);

  hipMemsetAsync(out, 0, (size_t)out_size * sizeof(float), stream);

  const int njt = (N + TILE - 1) / TILE;
  int jsplit = 8;
  if (jsplit > njt) jsplit = njt;
  const int tiles_per_split = (njt + jsplit - 1) / jsplit;
  const int splits = (njt + tiles_per_split - 1) / tiles_per_split;

  dim3 grid(njt, splits, B);
  grav_kernel<<<grid, TILE, 0, stream>>>(q, m, out, B, N, tiles_per_split);
}

// Round 3
// 41.084 us; speedup vs baseline: 1.0167x; 1.0167x over previous
//
#include <hip/hip_runtime.h>

typedef float v4f __attribute__((ext_vector_type(4)));

#define TILE 256        // j's staged per block
#define IPT 2           // i-particles per thread
#define G_CONST 0.001f
#define EPS_CONST 1e-6f

// Grid: (N/(TILE*IPT) i-blocks, N/TILE j-splits, B batches), 256 thr/block.
// Each block: stage one 256-j tile (SoA) in LDS once, then 512 i x 256 j pairs.
__global__ __launch_bounds__(256, 4)
void grav_kernel(const float* __restrict__ q, const float* __restrict__ m,
                 float* __restrict__ out, int N) {
  const int b   = blockIdx.z;
  const int tid = threadIdx.x;
  const int j0  = blockIdx.y * TILE;

  __shared__ float xs[TILE], ys[TILE], zs[TILE], ms[TILE];
  __shared__ float wsum[4];

  const float* qb = q + (size_t)b * N * 3;

  // Stage j tile (SoA so inner loop reads are broadcast ds_read_b128)
  {
    const int j = j0 + tid;
    xs[tid] = qb[3 * j + 0];
    ys[tid] = qb[3 * j + 1];
    zs[tid] = qb[3 * j + 2];
    ms[tid] = m[j];
  }

  // Per-thread i-slot data, splatted to v4f once (loop-invariant).
  v4f xi4[IPT], yi4[IPT], zi4[IPT];
  float mi[IPT];
  int   ii[IPT];
#pragma unroll
  for (int s = 0; s < IPT; ++s) {
    const int i = blockIdx.x * (TILE * IPT) + s * TILE + tid;
    ii[s] = i;
    const float x = qb[3 * i + 0];
    const float y = qb[3 * i + 1];
    const float z = qb[3 * i + 2];
    xi4[s] = (v4f){x, x, x, x};
    yi4[s] = (v4f){y, y, y, y};
    zi4[s] = (v4f){z, z, z, z};
    mi[s]  = m[i];
  }

  __syncthreads();

  const v4f eps4 = {EPS_CONST, EPS_CONST, EPS_CONST, EPS_CONST};
  v4f acc[IPT] = {};

  for (int k = 0; k < TILE; k += 4) {
    const v4f jx = *(const v4f*)&xs[k];   // broadcast reads: all lanes same addr
    const v4f jy = *(const v4f*)&ys[k];
    const v4f jz = *(const v4f*)&zs[k];
    const v4f jm = *(const v4f*)&ms[k];
#pragma unroll
    for (int s = 0; s < IPT; ++s) {
      const v4f dx = jx - xi4[s];
      const v4f dy = jy - yi4[s];
      const v4f dz = jz - zi4[s];
      v4f r2 = __builtin_elementwise_fma(dz, dz, eps4);
      r2 = __builtin_elementwise_fma(dy, dy, r2);
      r2 = __builtin_elementwise_fma(dx, dx, r2);
      const v4f ri = {__builtin_amdgcn_rsqf(r2.x), __builtin_amdgcn_rsqf(r2.y),
                      __builtin_amdgcn_rsqf(r2.z), __builtin_amdgcn_rsqf(r2.w)};
      acc[s] = __builtin_elementwise_fma(jm, ri, acc[s]);
    }
  }

  // Reduce + self-term removal. At i==j the loop computed r2 == EPS exactly
  // (fma(0,0,...) chain) and contributed m_i * rsq(EPS) to acc, so subtract
  // exactly that (R2 bug: the mi factor was missing -> +341 systematic error).
  float tsum = 0.f;
#pragma unroll
  for (int s = 0; s < IPT; ++s) {
    float h = (acc[s].x + acc[s].y) + (acc[s].z + acc[s].w);
    if (ii[s] >= j0 && ii[s] < j0 + TILE)
      h -= mi[s] * __builtin_amdgcn_rsqf(EPS_CONST);
    tsum += mi[s] * h;
  }

  // Block reduction: 64-lane shuffle, then across 4 waves via LDS.
#pragma unroll
  for (int off = 32; off > 0; off >>= 1) tsum += __shfl_down(tsum, off);
  const int wid  = tid >> 6;
  const int lane = tid & 63;
  if (lane == 0) wsum[wid] = tsum;
  __syncthreads();
  if (tid == 0) {
    const float s = (wsum[0] + wsum[1]) + (wsum[2] + wsum[3]);
    atomicAdd(out + b, s * (-0.5f * G_CONST));
  }
}

extern "C" void kernel_launch(void* const* d_in, const int* in_sizes, int n_in,
                              void* d_out, int out_size, void* d_ws, size_t ws_size,
                              hipStream_t stream) {
  const float* q = (const float*)d_in[0];
  const float* m = (const float*)d_in[1];
  float* out = (float*)d_out;

  const int N = in_sizes[1];
  const int B = in_sizes[0] / (N * 3);

  hipMemsetAsync(out, 0, (size_t)out_size * sizeof(float), stream);

  dim3 grid(N / (TILE * IPT), N / TILE, B);   // 8 x 16 x 8 = 1024 blocks
  grav_kernel<<<grid, TILE, 0, stream>>>(q, m, out, N);
}